// Round 2
// baseline (268.904 us; speedup 1.0000x reference)
//
#include <hip/hip_runtime.h>
#include <hip/hip_bf16.h>
#include <stdint.h>

typedef _Float16 f16;
typedef _Float16 f16x8 __attribute__((ext_vector_type(8)));
typedef _Float16 f16x4 __attribute__((ext_vector_type(4)));
typedef float    f32x4 __attribute__((ext_vector_type(4)));

#define BB 4
#define CC 512
#define TT 2048

__device__ __forceinline__ void gload16(const void* g, void* l) {
  __builtin_amdgcn_global_load_lds((const __attribute__((address_space(1))) void*)g,
                                   (__attribute__((address_space(3))) void*)l, 16, 0, 0);
}

// ---------------- instance-norm stats (mean, rsqrt(var+eps)) per (b,c) ----------------
__global__ __launch_bounds__(256) void stats_kernel(
    const float* __restrict__ xc, const float* __restrict__ xs,
    float* __restrict__ meanc, float* __restrict__ invc,
    float* __restrict__ means, float* __restrict__ invs) {
  const int c = blockIdx.x, b = blockIdx.y, which = blockIdx.z;
  const float* src = (which ? xs : xc) + ((long)b * CC + c) * TT;
  const int tid = threadIdx.x;
  const float4* p4 = (const float4*)src;
  float4 a = p4[tid * 2], d = p4[tid * 2 + 1];
  float s = a.x + a.y + a.z + a.w + d.x + d.y + d.z + d.w;
  float q = a.x*a.x + a.y*a.y + a.z*a.z + a.w*a.w + d.x*d.x + d.y*d.y + d.z*d.z + d.w*d.w;
  #pragma unroll
  for (int o = 32; o; o >>= 1) { s += __shfl_xor(s, o); q += __shfl_xor(q, o); }
  __shared__ float sred[4], qred[4];
  if ((tid & 63) == 0) { sred[tid >> 6] = s; qred[tid >> 6] = q; }
  __syncthreads();
  if (tid == 0) {
    float S = sred[0] + sred[1] + sred[2] + sred[3];
    float Q = qred[0] + qred[1] + qred[2] + qred[3];
    float mean = S * (1.f / TT);
    float var  = Q * (1.f / TT) - mean * mean;
    float inv  = 1.0f / sqrtf(var + 1e-5f);
    float* mp = which ? means : meanc;
    float* ip = which ? invs  : invc;
    mp[b * CC + c] = mean;
    ip[b * CC + c] = inv;
  }
}

// ---------------- f32 [C][T] -> f16 [T][C] tiled transpose ----------------
__global__ __launch_bounds__(256) void transpose_kernel(
    const float* __restrict__ xc, const float* __restrict__ xs,
    f16* __restrict__ xcT, f16* __restrict__ xsT) {
  const int b = blockIdx.z & 3, which = blockIdx.z >> 2;
  const float* src = (which ? xs : xc) + (long)b * CC * TT;
  f16* dst = (which ? xsT : xcT) + (long)b * TT * CC;
  const int t0 = blockIdx.x * 64, c0 = blockIdx.y * 64;
  __shared__ float tile[64][65];
  const int tid = threadIdx.x;
  #pragma unroll
  for (int it = 0; it < 4; ++it) {
    int s = it * 256 + tid, r = s >> 4, q = s & 15;
    float4 v = *(const float4*)&src[(long)(c0 + r) * TT + t0 + q * 4];
    tile[r][q*4+0] = v.x; tile[r][q*4+1] = v.y; tile[r][q*4+2] = v.z; tile[r][q*4+3] = v.w;
  }
  __syncthreads();
  #pragma unroll
  for (int it = 0; it < 4; ++it) {
    int s = it * 256 + tid, r = s >> 4, q = s & 15;
    f16x4 o;
    o[0] = (f16)tile[q*4+0][r]; o[1] = (f16)tile[q*4+1][r];
    o[2] = (f16)tile[q*4+2][r]; o[3] = (f16)tile[q*4+3][r];
    *(f16x4*)&dst[(long)(t0 + r) * CC + c0 + q * 4] = o;
  }
}

// ---------------- fold instance-norm into conv weights ----------------
__global__ __launch_bounds__(256) void prepw_kernel(
    const float* __restrict__ W, const float* __restrict__ bias,
    const float* __restrict__ mean, const float* __restrict__ inv,
    f16* __restrict__ Weff, float* __restrict__ beff) {
  const int o = blockIdx.x, b = blockIdx.y, tid = threadIdx.x;
  float acc = 0.f;
  #pragma unroll
  for (int j = 0; j < 2; ++j) {
    int c = tid + j * 256;
    float iv = inv[b * CC + c];
    float wv = W[(long)o * CC + c] * iv;
    Weff[((long)b * CC + o) * CC + c] = (f16)wv;
    acc += wv * mean[b * CC + c];
  }
  #pragma unroll
  for (int off = 32; off; off >>= 1) acc += __shfl_xor(acc, off);
  __shared__ float red[4];
  if ((tid & 63) == 0) red[tid >> 6] = acc;
  __syncthreads();
  if (tid == 0) beff[b * CC + o] = bias[o] - (red[0] + red[1] + red[2] + red[3]);
}

// ---------------- f32 -> f16 convert (Wl, Wo) ----------------
__global__ __launch_bounds__(256) void f2h_kernel(const float* __restrict__ src,
                                                  f16* __restrict__ dst) {
  long i = ((long)blockIdx.x * 256 + threadIdx.x) * 8;
  float4 a = *(const float4*)&src[i], d = *(const float4*)&src[i + 4];
  f16x8 o;
  o[0]=(f16)a.x; o[1]=(f16)a.y; o[2]=(f16)a.z; o[3]=(f16)a.w;
  o[4]=(f16)d.x; o[5]=(f16)d.y; o[6]=(f16)d.z; o[7]=(f16)d.w;
  *(f16x8*)&dst[i] = o;
}

// ---------------- row softmax, f32 in place -> f16 packed into row head ----------------
__global__ __launch_bounds__(256) void softmax_kernel(float* __restrict__ S) {
  float* p = S + ((long)blockIdx.y * TT + blockIdx.x) * TT;
  const int tid = threadIdx.x;
  float4 a = ((const float4*)p)[tid * 2], d = ((const float4*)p)[tid * 2 + 1];
  float v[8] = {a.x, a.y, a.z, a.w, d.x, d.y, d.z, d.w};
  float m = v[0];
  #pragma unroll
  for (int j = 1; j < 8; ++j) m = fmaxf(m, v[j]);
  #pragma unroll
  for (int o = 32; o; o >>= 1) m = fmaxf(m, __shfl_xor(m, o));
  __shared__ float red[4], red2[4];
  if (!(tid & 63)) red[tid >> 6] = m;
  __syncthreads();
  m = fmaxf(fmaxf(red[0], red[1]), fmaxf(red[2], red[3]));
  float e[8], sum = 0.f;
  #pragma unroll
  for (int j = 0; j < 8; ++j) { e[j] = __expf(v[j] - m); sum += e[j]; }
  #pragma unroll
  for (int o = 32; o; o >>= 1) sum += __shfl_xor(sum, o);
  if (!(tid & 63)) red2[tid >> 6] = sum;
  __syncthreads();
  sum = red2[0] + red2[1] + red2[2] + red2[3];
  float is = 1.f / sum;
  f16x8 o8;
  #pragma unroll
  for (int j = 0; j < 8; ++j) o8[j] = (f16)(e[j] * is);
  ((f16x8*)p)[tid] = o8;
}

// ---------------- TN GEMM: C[M,N] = A[M,K] * BT[N,K]^T, 128x128 tile, mfma 16x16x32 f16 ----------------
template <typename OutT, bool TRANSW, bool BIAS, bool RESID>
__global__ __launch_bounds__(256) void gemm_kernel(
    const f16* __restrict__ A, long long sAb, int lda,
    const f16* __restrict__ BT, long long sBb, int ldb,
    OutT* __restrict__ C, long long sCb, int ldc,
    const float* __restrict__ bias, long long sBiasb,
    const float* __restrict__ resid, long long sResb, int ldres,
    int K) {
  const int b = blockIdx.z;
  A += (long long)b * sAb; BT += (long long)b * sBb; C += (long long)b * sCb;
  if (BIAS) bias += (long long)b * sBiasb;
  if (RESID) resid += (long long)b * sResb;
  const int bm = blockIdx.y * 128, bn = blockIdx.x * 128;
  const int tid = threadIdx.x, lane = tid & 63, wv = tid >> 6;
  const int wr = wv >> 1, wc = wv & 1;

  __shared__ f16 sA[128 * 32];
  __shared__ f16 sB[128 * 32];

  const int rS = lane >> 2, cS = lane & 3;
  const char* gA0 = (const char*)(A + (long)(bm + (wv*2+0)*16 + rS) * lda + cS * 8);
  const char* gA1 = (const char*)(A + (long)(bm + (wv*2+1)*16 + rS) * lda + cS * 8);
  const char* gB0 = (const char*)(BT + (long)(bn + (wv*2+0)*16 + rS) * ldb + cS * 8);
  const char* gB1 = (const char*)(BT + (long)(bn + (wv*2+1)*16 + rS) * ldb + cS * 8);
  char* lA0 = (char*)sA + (wv*2+0)*1024;
  char* lA1 = (char*)sA + (wv*2+1)*1024;
  char* lB0 = (char*)sB + (wv*2+0)*1024;
  char* lB1 = (char*)sB + (wv*2+1)*1024;

  const int lm = lane & 15, lk = (lane >> 4) * 8;
  f32x4 acc[4][4] = {};

  const int nk = K >> 5;
  for (int kt = 0; kt < nk; ++kt) {
    if (kt) __syncthreads();
    gload16(gA0 + (long)kt*64, lA0);
    gload16(gA1 + (long)kt*64, lA1);
    gload16(gB0 + (long)kt*64, lB0);
    gload16(gB1 + (long)kt*64, lB1);
    __syncthreads();
    f16x8 af[4], bfr[4];
    #pragma unroll
    for (int mi = 0; mi < 4; ++mi)
      af[mi] = *(const f16x8*)&sA[(wr*64 + mi*16 + lm)*32 + lk];
    #pragma unroll
    for (int ni = 0; ni < 4; ++ni)
      bfr[ni] = *(const f16x8*)&sB[(wc*64 + ni*16 + lm)*32 + lk];
    #pragma unroll
    for (int mi = 0; mi < 4; ++mi)
      #pragma unroll
      for (int ni = 0; ni < 4; ++ni)
        acc[mi][ni] = __builtin_amdgcn_mfma_f32_16x16x32_f16(af[mi], bfr[ni], acc[mi][ni], 0, 0, 0);
  }

  const int rr = (lane >> 4) * 4;
  #pragma unroll
  for (int mi = 0; mi < 4; ++mi) {
    int m0 = bm + wr*64 + mi*16 + rr;
    #pragma unroll
    for (int ni = 0; ni < 4; ++ni) {
      int n0 = bn + wc*64 + ni*16 + lm;
      f32x4 v = acc[mi][ni];
      #pragma unroll
      for (int r = 0; r < 4; ++r) {
        float val = v[r];
        if (BIAS)  val += bias[m0 + r];
        if (RESID) val += resid[(long)(m0 + r) * ldres + n0];
        if (TRANSW) C[(long)n0 * ldc + m0 + r] = (OutT)val;
        else        C[(long)(m0 + r) * ldc + n0] = (OutT)val;
      }
    }
  }
}

extern "C" void kernel_launch(void* const* d_in, const int* in_sizes, int n_in,
                              void* d_out, int out_size, void* d_ws, size_t ws_size,
                              hipStream_t stream) {
  const float* x_c = (const float*)d_in[0];
  const float* x_s = (const float*)d_in[1];
  const float* Wn  = (const float*)d_in[2];
  const float* bn  = (const float*)d_in[3];
  const float* Wm  = (const float*)d_in[4];
  const float* bm  = (const float*)d_in[5];
  const float* Wl  = (const float*)d_in[6];
  const float* bl  = (const float*)d_in[7];
  const float* Wo  = (const float*)d_in[8];
  const float* bo  = (const float*)d_in[9];
  float* out = (float*)d_out;

  char* w = (char*)d_ws;
  auto alloc = [&](size_t bytes) { char* p = w; w += (bytes + 255) & ~(size_t)255; return p; };
  float* meanc = (float*)alloc(BB * CC * 4);
  float* invc  = (float*)alloc(BB * CC * 4);
  float* means = (float*)alloc(BB * CC * 4);
  float* invs  = (float*)alloc(BB * CC * 4);
  float* bnE   = (float*)alloc(BB * CC * 4);
  float* bmE   = (float*)alloc(BB * CC * 4);
  f16* WnE = (f16*)alloc((size_t)BB * CC * CC * 2);
  f16* WmE = (f16*)alloc((size_t)BB * CC * CC * 2);
  f16* WlB = (f16*)alloc((size_t)CC * CC * 2);
  f16* WoB = (f16*)alloc((size_t)CC * CC * 2);
  f16* xcT = (f16*)alloc((size_t)BB * TT * CC * 2);
  f16* xsT = (f16*)alloc((size_t)BB * TT * CC * 2);
  f16* MnT = (f16*)alloc((size_t)BB * TT * CC * 2);
  f16* MmT = (f16*)alloc((size_t)BB * TT * CC * 2);
  f16* Ml  = (f16*)alloc((size_t)BB * CC * TT * 2);
  float* S  = (float*)alloc((size_t)BB * TT * TT * 4);
  f16* MoT = (f16*)alloc((size_t)BB * TT * CC * 2);

  dim3 blk(256);

  stats_kernel<<<dim3(CC, BB, 2), blk, 0, stream>>>(x_c, x_s, meanc, invc, means, invs);
  transpose_kernel<<<dim3(TT / 64, CC / 64, BB * 2), blk, 0, stream>>>(x_c, x_s, xcT, xsT);
  prepw_kernel<<<dim3(CC, BB), blk, 0, stream>>>(Wn, bn, meanc, invc, WnE, bnE);
  prepw_kernel<<<dim3(CC, BB), blk, 0, stream>>>(Wm, bm, means, invs, WmE, bmE);
  f2h_kernel<<<dim3(CC * CC / (256 * 8)), blk, 0, stream>>>(Wl, WlB);
  f2h_kernel<<<dim3(CC * CC / (256 * 8)), blk, 0, stream>>>(Wo, WoB);

  // MnT[t][o] = Wn'[b] @ xc ; transposed write, bias on M
  gemm_kernel<f16, true, true, false><<<dim3(16, 4, BB), blk, 0, stream>>>(
      WnE, (long long)CC * CC, CC, xcT, (long long)TT * CC, CC,
      MnT, (long long)TT * CC, CC, bnE, CC, nullptr, 0, 0, CC);
  // MmT[s][o]
  gemm_kernel<f16, true, true, false><<<dim3(16, 4, BB), blk, 0, stream>>>(
      WmE, (long long)CC * CC, CC, xsT, (long long)TT * CC, CC,
      MmT, (long long)TT * CC, CC, bmE, CC, nullptr, 0, 0, CC);
  // Ml[c][s] = Wl @ xs ; normal write, bias on M
  gemm_kernel<f16, false, true, false><<<dim3(16, 4, BB), blk, 0, stream>>>(
      WlB, 0, CC, xsT, (long long)TT * CC, CC,
      Ml, (long long)CC * TT, TT, bl, 0, nullptr, 0, 0, CC);
  // S[t][s] = MnT @ MmT^T (f32)
  gemm_kernel<float, false, false, false><<<dim3(16, 16, BB), blk, 0, stream>>>(
      MnT, (long long)TT * CC, CC, MmT, (long long)TT * CC, CC,
      S, (long long)TT * TT, TT, nullptr, 0, nullptr, 0, 0, CC);
  // softmax rows -> f16 P packed in place (lda = 2*TT f16 elems)
  softmax_kernel<<<dim3(TT, BB), blk, 0, stream>>>(S);
  // MoT[t][c] = P @ Ml^T
  gemm_kernel<f16, false, false, false><<<dim3(4, 16, BB), blk, 0, stream>>>(
      (const f16*)S, (long long)TT * 2 * TT, 2 * TT, Ml, (long long)CC * TT, TT,
      MoT, (long long)TT * CC, CC, nullptr, 0, nullptr, 0, 0, TT);
  // out[o][t] = Wo @ MoT^T + bo + x_c
  gemm_kernel<float, false, true, true><<<dim3(16, 4, BB), blk, 0, stream>>>(
      WoB, 0, CC, MoT, (long long)TT * CC, CC,
      out, (long long)CC * TT, TT, bo, 0, x_c, (long long)CC * TT, TT, CC);
}

// Round 4
// 239.507 us; speedup vs baseline: 1.1227x; 1.1227x over previous
//
#include <hip/hip_runtime.h>
#include <hip/hip_bf16.h>
#include <stdint.h>

typedef _Float16 f16;
typedef _Float16 f16x8 __attribute__((ext_vector_type(8)));
typedef _Float16 f16x4 __attribute__((ext_vector_type(4)));
typedef float    f32x4 __attribute__((ext_vector_type(4)));

#define BB 4
#define CC 512
#define TT 2048

__device__ __forceinline__ void gload16(const void* g, void* l) {
  __builtin_amdgcn_global_load_lds((const __attribute__((address_space(1))) void*)g,
                                   (__attribute__((address_space(3))) void*)l, 16, 0, 0);
}

// ---------------- instance-norm stats ----------------
__global__ __launch_bounds__(256) void stats_kernel(
    const float* __restrict__ xc, const float* __restrict__ xs,
    float* __restrict__ meanc, float* __restrict__ invc,
    float* __restrict__ means, float* __restrict__ invs) {
  const int c = blockIdx.x, b = blockIdx.y, which = blockIdx.z;
  const float* src = (which ? xs : xc) + ((long)b * CC + c) * TT;
  const int tid = threadIdx.x;
  const float4* p4 = (const float4*)src;
  float4 a = p4[tid * 2], d = p4[tid * 2 + 1];
  float s = a.x + a.y + a.z + a.w + d.x + d.y + d.z + d.w;
  float q = a.x*a.x + a.y*a.y + a.z*a.z + a.w*a.w + d.x*d.x + d.y*d.y + d.z*d.z + d.w*d.w;
  #pragma unroll
  for (int o = 32; o; o >>= 1) { s += __shfl_xor(s, o); q += __shfl_xor(q, o); }
  __shared__ float sred[4], qred[4];
  if ((tid & 63) == 0) { sred[tid >> 6] = s; qred[tid >> 6] = q; }
  __syncthreads();
  if (tid == 0) {
    float S = sred[0] + sred[1] + sred[2] + sred[3];
    float Q = qred[0] + qred[1] + qred[2] + qred[3];
    float mean = S * (1.f / TT);
    float var  = Q * (1.f / TT) - mean * mean;
    float inv  = 1.0f / sqrtf(var + 1e-5f);
    (which ? means : meanc)[b * CC + c] = mean;
    (which ? invs  : invc )[b * CC + c] = inv;
  }
}

// ---------------- f32 [C][T] -> f16 [T][C] transpose ----------------
__global__ __launch_bounds__(256) void transpose_kernel(
    const float* __restrict__ xc, const float* __restrict__ xs,
    f16* __restrict__ xcT, f16* __restrict__ xsT) {
  const int b = blockIdx.z & 3, which = blockIdx.z >> 2;
  const float* src = (which ? xs : xc) + (long)b * CC * TT;
  f16* dst = (which ? xsT : xcT) + (long)b * TT * CC;
  const int t0 = blockIdx.x * 64, c0 = blockIdx.y * 64;
  __shared__ float tile[64][65];
  const int tid = threadIdx.x;
  #pragma unroll
  for (int it = 0; it < 4; ++it) {
    int s = it * 256 + tid, r = s >> 4, q = s & 15;
    float4 v = *(const float4*)&src[(long)(c0 + r) * TT + t0 + q * 4];
    tile[r][q*4+0] = v.x; tile[r][q*4+1] = v.y; tile[r][q*4+2] = v.z; tile[r][q*4+3] = v.w;
  }
  __syncthreads();
  #pragma unroll
  for (int it = 0; it < 4; ++it) {
    int s = it * 256 + tid, r = s >> 4, q = s & 15;
    f16x4 o;
    o[0] = (f16)tile[q*4+0][r]; o[1] = (f16)tile[q*4+1][r];
    o[2] = (f16)tile[q*4+2][r]; o[3] = (f16)tile[q*4+3][r];
    *(f16x4*)&dst[(long)(t0 + r) * CC + c0 + q * 4] = o;
  }
}

// ---------------- fold instance-norm into conv weights ----------------
__global__ __launch_bounds__(256) void prepw_kernel(
    const float* __restrict__ W, const float* __restrict__ bias,
    const float* __restrict__ mean, const float* __restrict__ inv,
    f16* __restrict__ Weff, float* __restrict__ beff) {
  const int o = blockIdx.x, b = blockIdx.y, tid = threadIdx.x;
  float acc = 0.f;
  #pragma unroll
  for (int j = 0; j < 2; ++j) {
    int c = tid + j * 256;
    float iv = inv[b * CC + c];
    float wv = W[(long)o * CC + c] * iv;
    Weff[((long)b * CC + o) * CC + c] = (f16)wv;
    acc += wv * mean[b * CC + c];
  }
  #pragma unroll
  for (int off = 32; off; off >>= 1) acc += __shfl_xor(acc, off);
  __shared__ float red[4];
  if ((tid & 63) == 0) red[tid >> 6] = acc;
  __syncthreads();
  if (tid == 0) beff[b * CC + o] = bias[o] - (red[0] + red[1] + red[2] + red[3]);
}

// ---------------- f32 -> f16 convert ----------------
__global__ __launch_bounds__(256) void f2h_kernel(const float* __restrict__ src,
                                                  f16* __restrict__ dst) {
  long i = ((long)blockIdx.x * 256 + threadIdx.x) * 8;
  float4 a = *(const float4*)&src[i], d = *(const float4*)&src[i + 4];
  f16x8 o;
  o[0]=(f16)a.x; o[1]=(f16)a.y; o[2]=(f16)a.z; o[3]=(f16)a.w;
  o[4]=(f16)d.x; o[5]=(f16)d.y; o[6]=(f16)d.z; o[7]=(f16)d.w;
  *(f16x8*)&dst[i] = o;
}

// ---------------- row softmax: f32 in place -> f16 packed into row head ----------------
__global__ __launch_bounds__(256) void softmax_kernel(float* __restrict__ S) {
  float* p = S + ((long)blockIdx.y * TT + blockIdx.x) * TT;
  const int tid = threadIdx.x;
  float4 a = ((const float4*)p)[tid * 2], d = ((const float4*)p)[tid * 2 + 1];
  float v[8] = {a.x, a.y, a.z, a.w, d.x, d.y, d.z, d.w};
  float m = v[0];
  #pragma unroll
  for (int j = 1; j < 8; ++j) m = fmaxf(m, v[j]);
  #pragma unroll
  for (int o = 32; o; o >>= 1) m = fmaxf(m, __shfl_xor(m, o));
  __shared__ float red[4], red2[4];
  if (!(tid & 63)) red[tid >> 6] = m;
  __syncthreads();
  m = fmaxf(fmaxf(red[0], red[1]), fmaxf(red[2], red[3]));
  float e[8], sum = 0.f;
  #pragma unroll
  for (int j = 0; j < 8; ++j) { e[j] = __expf(v[j] - m); sum += e[j]; }
  #pragma unroll
  for (int o = 32; o; o >>= 1) sum += __shfl_xor(sum, o);
  if (!(tid & 63)) red2[tid >> 6] = sum;
  __syncthreads();
  sum = red2[0] + red2[1] + red2[2] + red2[3];
  float is = 1.f / sum;
  f16x8 o8;
  #pragma unroll
  for (int j = 0; j < 8; ++j) o8[j] = (f16)(e[j] * is);
  ((f16x8*)p)[tid] = o8;
}

// ======================= 2-phase prefetched GEMM core =======================
// C[M,N] = A[M,K] * BT[N,K]^T. 512 threads (8 waves, 4x2), tile 128x128, BK=64.
// LDS XOR-swizzle (row&7)<<4 applied to staging SOURCE + ds_read (dest linear).
template <typename OutT>
__device__ __forceinline__ void gemm_core(
    const f16* __restrict__ A, int lda,
    const f16* __restrict__ BT, int ldb,
    OutT* __restrict__ C, int ldc,
    const float* __restrict__ bias,
    const float* __restrict__ resid, int ldres,
    int bm, int bn, int K, bool transw) {

  __shared__ f16 sA[2][128 * 64];
  __shared__ f16 sB[2][128 * 64];

  const int tid = threadIdx.x, lane = tid & 63, wv = tid >> 6;
  const int wr = wv >> 1, wc = wv & 1;   // wave tile: rows wr*32, cols wc*64

  // ---- staging addresses (thread covers 2 rows per operand) ----
  const int srow  = tid >> 3;                    // 0..63
  const int scolb = (tid & 7) * 16;              // byte within 128B row
  const int sgcolb = scolb ^ ((srow & 7) << 4);  // pre-swizzled source col
  const char* gA  = (const char*)A  + (long)(bm + srow) * lda * 2 + sgcolb;
  const char* gA2 = gA + (long)64 * lda * 2;
  const char* gB  = (const char*)BT + (long)(bn + srow) * ldb * 2 + sgcolb;
  const char* gB2 = gB + (long)64 * ldb * 2;
  char* lA  = (char*)&sA[0][0] + tid * 16;
  char* lB  = (char*)&sB[0][0] + tid * 16;

  // ---- fragment ds_read byte offsets (within a 16KB buffer) ----
  const int lm = lane & 15, lkb = (lane >> 4) * 16, sw = (lane & 7) << 4;
  int aoff[2][2], boff[4][2];
  #pragma unroll
  for (int mi = 0; mi < 2; ++mi) {
    int r = wr * 32 + mi * 16 + lm;
    #pragma unroll
    for (int kk = 0; kk < 2; ++kk)
      aoff[mi][kk] = r * 128 + ((kk * 64 + lkb) ^ sw);
  }
  #pragma unroll
  for (int ni = 0; ni < 4; ++ni) {
    int r = wc * 64 + ni * 16 + lm;
    #pragma unroll
    for (int kk = 0; kk < 2; ++kk)
      boff[ni][kk] = r * 128 + ((kk * 64 + lkb) ^ sw);
  }

  f32x4 acc[2][4] = {};
  const int nk = K >> 6;

  // prologue
  {
    gload16(gA, lA); gload16(gA2, lA + 8192);
    gload16(gB, lB); gload16(gB2, lB + 8192);
  }
  __syncthreads();

  int cur = 0;
  for (int kt = 0; kt < nk; ++kt) {
    if (kt + 1 < nk) {
      long kb = (long)(kt + 1) * 128;
      int nb = (cur ^ 1) * 16384;
      gload16(gA + kb, lA + nb); gload16(gA2 + kb, lA + nb + 8192);
      gload16(gB + kb, lB + nb); gload16(gB2 + kb, lB + nb + 8192);
    }
    const char* pa = (const char*)&sA[cur][0];
    const char* pb = (const char*)&sB[cur][0];
    f16x8 af[2][2], bf[4][2];
    #pragma unroll
    for (int mi = 0; mi < 2; ++mi)
      #pragma unroll
      for (int kk = 0; kk < 2; ++kk)
        af[mi][kk] = *(const f16x8*)(pa + aoff[mi][kk]);
    #pragma unroll
    for (int ni = 0; ni < 4; ++ni)
      #pragma unroll
      for (int kk = 0; kk < 2; ++kk)
        bf[ni][kk] = *(const f16x8*)(pb + boff[ni][kk]);
    #pragma unroll
    for (int kk = 0; kk < 2; ++kk)
      #pragma unroll
      for (int mi = 0; mi < 2; ++mi)
        #pragma unroll
        for (int ni = 0; ni < 4; ++ni)
          acc[mi][ni] = __builtin_amdgcn_mfma_f32_16x16x32_f16(af[mi][kk], bf[ni][kk], acc[mi][ni], 0, 0, 0);
    __syncthreads();
    cur ^= 1;
  }

  // ---- epilogue ----
  struct alignas(4 * sizeof(OutT)) Pack4 { OutT v[4]; };
  const int rr = (lane >> 4) * 4;
  #pragma unroll
  for (int mi = 0; mi < 2; ++mi) {
    int m0 = bm + wr * 32 + mi * 16 + rr;
    #pragma unroll
    for (int ni = 0; ni < 4; ++ni) {
      int n0 = bn + wc * 64 + ni * 16 + lm;
      f32x4 v = acc[mi][ni];
      float vals[4];
      #pragma unroll
      for (int r = 0; r < 4; ++r) {
        vals[r] = v[r];
        if (bias)  vals[r] += bias[m0 + r];
        if (resid) vals[r] += resid[(long)(m0 + r) * ldres + n0];
      }
      if (transw) {
        Pack4 pk;
        #pragma unroll
        for (int r = 0; r < 4; ++r) pk.v[r] = (OutT)vals[r];
        *(Pack4*)&C[(long)n0 * ldc + m0] = pk;
      } else {
        #pragma unroll
        for (int r = 0; r < 4; ++r)
          C[(long)(m0 + r) * ldc + n0] = (OutT)vals[r];
      }
    }
  }
}

// ---- merged conv GEMMs: z = cid*4 + b ----
__global__ __launch_bounds__(512) void conv_kernel(
    const f16* __restrict__ xcT, const f16* __restrict__ xsT,
    const f16* __restrict__ WnE, const float* __restrict__ bnE,
    const f16* __restrict__ WmE, const float* __restrict__ bmE,
    const f16* __restrict__ WlB, const float* __restrict__ bl,
    f16* __restrict__ MnT, f16* __restrict__ MmT, f16* __restrict__ Ml) {
  const int z = blockIdx.z, cid = z >> 2, b = z & 3;
  const f16* A; const float* bias; const f16* B; f16* C; int ldc; bool transw;
  if (cid == 0)      { A = WnE + (long)b*CC*CC; bias = bnE + b*CC; B = xcT + (long)b*TT*CC; C = MnT + (long)b*TT*CC; ldc = CC; transw = true; }
  else if (cid == 1) { A = WmE + (long)b*CC*CC; bias = bmE + b*CC; B = xsT + (long)b*TT*CC; C = MmT + (long)b*TT*CC; ldc = CC; transw = true; }
  else               { A = WlB;                 bias = bl;         B = xsT + (long)b*TT*CC; C = Ml  + (long)b*CC*TT; ldc = TT; transw = false; }
  gemm_core<f16>(A, CC, B, CC, C, ldc, bias, nullptr, 0,
                 blockIdx.y * 128, blockIdx.x * 128, CC, transw);
}

__global__ __launch_bounds__(512) void sgemm_kernel(
    const f16* __restrict__ MnT, const f16* __restrict__ MmT, float* __restrict__ S) {
  const int b = blockIdx.z;
  gemm_core<float>(MnT + (long)b*TT*CC, CC, MmT + (long)b*TT*CC, CC,
                   S + (long)b*TT*TT, TT, nullptr, nullptr, 0,
                   blockIdx.y * 128, blockIdx.x * 128, CC, false);
}

__global__ __launch_bounds__(512) void pv_kernel(
    const f16* __restrict__ P, const f16* __restrict__ Ml, f16* __restrict__ MoT) {
  const int b = blockIdx.z;
  gemm_core<f16>(P + (long)b*TT*2*TT, 2*TT, Ml + (long)b*CC*TT, TT,
                 MoT + (long)b*TT*CC, CC, nullptr, nullptr, 0,
                 blockIdx.y * 128, blockIdx.x * 128, TT, false);
}

__global__ __launch_bounds__(512) void out_kernel(
    const f16* __restrict__ WoB, const f16* __restrict__ MoT,
    const float* __restrict__ bo, const float* __restrict__ xc, float* __restrict__ out) {
  const int b = blockIdx.z;
  gemm_core<float>(WoB, CC, MoT + (long)b*TT*CC, CC,
                   out + (long)b*CC*TT, TT, bo, xc + (long)b*CC*TT, TT,
                   blockIdx.y * 128, blockIdx.x * 128, CC, false);
}

extern "C" void kernel_launch(void* const* d_in, const int* in_sizes, int n_in,
                              void* d_out, int out_size, void* d_ws, size_t ws_size,
                              hipStream_t stream) {
  const float* x_c = (const float*)d_in[0];
  const float* x_s = (const float*)d_in[1];
  const float* Wn  = (const float*)d_in[2];
  const float* bn  = (const float*)d_in[3];
  const float* Wm  = (const float*)d_in[4];
  const float* bm  = (const float*)d_in[5];
  const float* Wl  = (const float*)d_in[6];
  const float* bl  = (const float*)d_in[7];
  const float* Wo  = (const float*)d_in[8];
  const float* bo  = (const float*)d_in[9];
  float* out = (float*)d_out;

  char* w = (char*)d_ws;
  auto alloc = [&](size_t bytes) { char* p = w; w += (bytes + 255) & ~(size_t)255; return p; };
  float* meanc = (float*)alloc(BB * CC * 4);
  float* invc  = (float*)alloc(BB * CC * 4);
  float* means = (float*)alloc(BB * CC * 4);
  float* invs  = (float*)alloc(BB * CC * 4);
  float* bnE   = (float*)alloc(BB * CC * 4);
  float* bmE   = (float*)alloc(BB * CC * 4);
  f16* WnE = (f16*)alloc((size_t)BB * CC * CC * 2);
  f16* WmE = (f16*)alloc((size_t)BB * CC * CC * 2);
  f16* WlB = (f16*)alloc((size_t)CC * CC * 2);
  f16* WoB = (f16*)alloc((size_t)CC * CC * 2);
  f16* xcT = (f16*)alloc((size_t)BB * TT * CC * 2);
  f16* xsT = (f16*)alloc((size_t)BB * TT * CC * 2);
  f16* MnT = (f16*)alloc((size_t)BB * TT * CC * 2);
  f16* MmT = (f16*)alloc((size_t)BB * TT * CC * 2);
  f16* Ml  = (f16*)alloc((size_t)BB * CC * TT * 2);
  float* S  = (float*)alloc((size_t)BB * TT * TT * 4);
  f16* MoT = (f16*)alloc((size_t)BB * TT * CC * 2);

  stats_kernel<<<dim3(CC, BB, 2), dim3(256), 0, stream>>>(x_c, x_s, meanc, invc, means, invs);
  transpose_kernel<<<dim3(TT / 64, CC / 64, BB * 2), dim3(256), 0, stream>>>(x_c, x_s, xcT, xsT);
  prepw_kernel<<<dim3(CC, BB), dim3(256), 0, stream>>>(Wn, bn, meanc, invc, WnE, bnE);
  prepw_kernel<<<dim3(CC, BB), dim3(256), 0, stream>>>(Wm, bm, means, invs, WmE, bmE);
  f2h_kernel<<<dim3(CC * CC / (256 * 8)), dim3(256), 0, stream>>>(Wl, WlB);
  f2h_kernel<<<dim3(CC * CC / (256 * 8)), dim3(256), 0, stream>>>(Wo, WoB);

  conv_kernel<<<dim3(16, 4, 12), dim3(512), 0, stream>>>(
      xcT, xsT, WnE, bnE, WmE, bmE, WlB, bl, MnT, MmT, Ml);
  sgemm_kernel<<<dim3(16, 16, BB), dim3(512), 0, stream>>>(MnT, MmT, S);
  softmax_kernel<<<dim3(TT, BB), dim3(256), 0, stream>>>(S);
  pv_kernel<<<dim3(4, 16, BB), dim3(512), 0, stream>>>((const f16*)S, Ml, MoT);
  out_kernel<<<dim3(16, 4, BB), dim3(512), 0, stream>>>(WoB, MoT, bo, x_c, out);
}

// Round 5
// 234.797 us; speedup vs baseline: 1.1453x; 1.0201x over previous
//
#include <hip/hip_runtime.h>
#include <hip/hip_bf16.h>
#include <stdint.h>

typedef _Float16 f16;
typedef _Float16 f16x8 __attribute__((ext_vector_type(8)));
typedef _Float16 f16x4 __attribute__((ext_vector_type(4)));
typedef float    f32x4 __attribute__((ext_vector_type(4)));

#define BB 4
#define CC 512
#define TT 2048

__device__ __forceinline__ void gload16(const void* g, void* l) {
  __builtin_amdgcn_global_load_lds((const __attribute__((address_space(1))) void*)g,
                                   (__attribute__((address_space(3))) void*)l, 16, 0, 0);
}

// XCD-chunked bijective block swizzle (requires total % 8 == 0)
__device__ __forceinline__ void xcd_swizzle(int& bx, int& by, int& bz) {
  int gx = gridDim.x, gy = gridDim.y;
  int F = bx + gx * (by + gy * bz);
  int q = (gx * gy * gridDim.z) >> 3;
  int l = (F & 7) * q + (F >> 3);
  bx = l % gx; by = (l / gx) % gy; bz = l / (gx * gy);
}

// ---------------- f32 [C][T] -> f16 [T][C] transpose + fused instance-norm sums ----------------
__global__ __launch_bounds__(256) void transpose_kernel(
    const float* __restrict__ xc, const float* __restrict__ xs,
    f16* __restrict__ xcT, f16* __restrict__ xsT,
    float* __restrict__ sumc, float* __restrict__ sqc,
    float* __restrict__ sums_, float* __restrict__ sqs) {
  const int b = blockIdx.z & 3, which = blockIdx.z >> 2;
  const float* src = (which ? xs : xc) + (long)b * CC * TT;
  f16* dst = (which ? xsT : xcT) + (long)b * TT * CC;
  float* sumP = (which ? sums_ : sumc) + b * CC;
  float* sqP  = (which ? sqs   : sqc ) + b * CC;
  const int t0 = blockIdx.x * 64, c0 = blockIdx.y * 64;
  __shared__ float tile[64][65];
  const int tid = threadIdx.x;
  #pragma unroll
  for (int it = 0; it < 4; ++it) {
    int s = it * 256 + tid, r = s >> 4, q = s & 15;
    float4 v = *(const float4*)&src[(long)(c0 + r) * TT + t0 + q * 4];
    tile[r][q*4+0] = v.x; tile[r][q*4+1] = v.y; tile[r][q*4+2] = v.z; tile[r][q*4+3] = v.w;
    float ps = v.x + v.y + v.z + v.w;
    float pq = v.x*v.x + v.y*v.y + v.z*v.z + v.w*v.w;
    #pragma unroll
    for (int o = 8; o; o >>= 1) { ps += __shfl_xor(ps, o); pq += __shfl_xor(pq, o); }
    if ((tid & 15) == 0) {
      atomicAdd(&sumP[c0 + r], ps);
      atomicAdd(&sqP [c0 + r], pq);
    }
  }
  __syncthreads();
  #pragma unroll
  for (int it = 0; it < 4; ++it) {
    int s = it * 256 + tid, r = s >> 4, q = s & 15;
    f16x4 o;
    o[0] = (f16)tile[q*4+0][r]; o[1] = (f16)tile[q*4+1][r];
    o[2] = (f16)tile[q*4+2][r]; o[3] = (f16)tile[q*4+3][r];
    *(f16x4*)&dst[(long)(t0 + r) * CC + c0 + q * 4] = o;
  }
}

// ---------------- fold instance-norm into conv weights (from raw sums) ----------------
__global__ __launch_bounds__(256) void prepw_kernel(
    const float* __restrict__ W, const float* __restrict__ bias,
    const float* __restrict__ sum, const float* __restrict__ sq,
    f16* __restrict__ Weff, float* __restrict__ beff) {
  const int o = blockIdx.x, b = blockIdx.y, tid = threadIdx.x;
  float acc = 0.f;
  #pragma unroll
  for (int j = 0; j < 2; ++j) {
    int c = tid + j * 256;
    float mean = sum[b * CC + c] * (1.f / TT);
    float var  = sq [b * CC + c] * (1.f / TT) - mean * mean;
    float iv = 1.0f / sqrtf(var + 1e-5f);
    float wv = W[(long)o * CC + c] * iv;
    Weff[((long)b * CC + o) * CC + c] = (f16)wv;
    acc += wv * mean;
  }
  #pragma unroll
  for (int off = 32; off; off >>= 1) acc += __shfl_xor(acc, off);
  __shared__ float red[4];
  if ((tid & 63) == 0) red[tid >> 6] = acc;
  __syncthreads();
  if (tid == 0) beff[b * CC + o] = bias[o] - (red[0] + red[1] + red[2] + red[3]);
}

// ---------------- f32 -> f16 convert ----------------
__global__ __launch_bounds__(256) void f2h_kernel(const float* __restrict__ src,
                                                  f16* __restrict__ dst) {
  long i = ((long)blockIdx.x * 256 + threadIdx.x) * 8;
  float4 a = *(const float4*)&src[i], d = *(const float4*)&src[i + 4];
  f16x8 o;
  o[0]=(f16)a.x; o[1]=(f16)a.y; o[2]=(f16)a.z; o[3]=(f16)a.w;
  o[4]=(f16)d.x; o[5]=(f16)d.y; o[6]=(f16)d.z; o[7]=(f16)d.w;
  *(f16x8*)&dst[i] = o;
}

// ---------------- row softmax over f16 S, in place ----------------
__global__ __launch_bounds__(256) void softmax_kernel(f16* __restrict__ S) {
  f16* p = S + ((long)blockIdx.y * TT + blockIdx.x) * TT;
  const int tid = threadIdx.x;
  f16x8 v8 = ((const f16x8*)p)[tid];
  float v[8];
  #pragma unroll
  for (int j = 0; j < 8; ++j) v[j] = (float)v8[j];
  float m = v[0];
  #pragma unroll
  for (int j = 1; j < 8; ++j) m = fmaxf(m, v[j]);
  #pragma unroll
  for (int o = 32; o; o >>= 1) m = fmaxf(m, __shfl_xor(m, o));
  __shared__ float red[4], red2[4];
  if (!(tid & 63)) red[tid >> 6] = m;
  __syncthreads();
  m = fmaxf(fmaxf(red[0], red[1]), fmaxf(red[2], red[3]));
  float e[8], sum = 0.f;
  #pragma unroll
  for (int j = 0; j < 8; ++j) { e[j] = __expf(v[j] - m); sum += e[j]; }
  #pragma unroll
  for (int o = 32; o; o >>= 1) sum += __shfl_xor(sum, o);
  if (!(tid & 63)) red2[tid >> 6] = sum;
  __syncthreads();
  sum = red2[0] + red2[1] + red2[2] + red2[3];
  float is = 1.f / sum;
  f16x8 o8;
  #pragma unroll
  for (int j = 0; j < 8; ++j) o8[j] = (f16)(e[j] * is);
  ((f16x8*)p)[tid] = o8;
}

// ======================= 2-phase prefetched GEMM core =======================
// C[M,N] = A[M,K] * BT[N,K]^T. Tile BM x 128, BK=64, NT threads (NT/64 waves).
// Wave grid: wr = wv>>1 (M), wc = wv&1 (N); wave tile 32x64, acc[2][4].
// LDS XOR-swizzle (row&7)<<4 on staging SOURCE + ds_read (dest linear).
template <int BM, int NT, typename OutT>
__device__ __forceinline__ void gemm_core(
    const f16* __restrict__ A, int lda,
    const f16* __restrict__ BT, int ldb,
    OutT* __restrict__ C, int ldc,
    const float* __restrict__ bias,
    const float* __restrict__ resid, int ldres,
    int bm, int bn, int K, bool transw) {

  constexpr int CA = BM * 8 / NT;          // A chunks per thread
  constexpr int CB = 128 * 8 / NT;         // B chunks per thread
  constexpr int ABUFB = BM * 128;          // bytes per A buffer
  constexpr int BBUFB = 128 * 128;         // bytes per B buffer

  __shared__ f16 sA[2 * BM * 64];
  __shared__ f16 sB[2 * 128 * 64];

  const int tid = threadIdx.x, lane = tid & 63, wv = tid >> 6;
  const int wr = wv >> 1, wc = wv & 1;

  // ---- staging addresses ----
  const char* gAp[CA]; int lAo[CA];
  #pragma unroll
  for (int i = 0; i < CA; ++i) {
    int cid = tid + i * NT, row = cid >> 3;
    int colb = ((cid & 7) * 16) ^ ((row & 7) << 4);
    gAp[i] = (const char*)A + (long)(bm + row) * lda * 2 + colb;
    lAo[i] = cid * 16;
  }
  const char* gBp[CB]; int lBo[CB];
  #pragma unroll
  for (int i = 0; i < CB; ++i) {
    int cid = tid + i * NT, row = cid >> 3;
    int colb = ((cid & 7) * 16) ^ ((row & 7) << 4);
    gBp[i] = (const char*)BT + (long)(bn + row) * ldb * 2 + colb;
    lBo[i] = cid * 16;
  }

  // ---- fragment ds_read byte offsets ----
  const int lm = lane & 15, lkb = (lane >> 4) * 16, sw = (lane & 7) << 4;
  int aoff[2][2], boff[4][2];
  #pragma unroll
  for (int mi = 0; mi < 2; ++mi) {
    int r = wr * 32 + mi * 16 + lm;
    #pragma unroll
    for (int kk = 0; kk < 2; ++kk)
      aoff[mi][kk] = r * 128 + ((kk * 64 + lkb) ^ sw);
  }
  #pragma unroll
  for (int ni = 0; ni < 4; ++ni) {
    int r = wc * 64 + ni * 16 + lm;
    #pragma unroll
    for (int kk = 0; kk < 2; ++kk)
      boff[ni][kk] = r * 128 + ((kk * 64 + lkb) ^ sw);
  }

  f32x4 acc[2][4] = {};
  const int nk = K >> 6;

  // prologue stage into buffer 0
  #pragma unroll
  for (int i = 0; i < CA; ++i) gload16(gAp[i], (char*)sA + lAo[i]);
  #pragma unroll
  for (int i = 0; i < CB; ++i) gload16(gBp[i], (char*)sB + lBo[i]);
  __syncthreads();

  int cur = 0;
  for (int kt = 0; kt < nk; ++kt) {
    if (kt + 1 < nk) {
      long kb = (long)(kt + 1) * 128;
      int na = (cur ^ 1) * ABUFB, nb = (cur ^ 1) * BBUFB;
      #pragma unroll
      for (int i = 0; i < CA; ++i) gload16(gAp[i] + kb, (char*)sA + na + lAo[i]);
      #pragma unroll
      for (int i = 0; i < CB; ++i) gload16(gBp[i] + kb, (char*)sB + nb + lBo[i]);
    }
    const char* pa = (const char*)sA + cur * ABUFB;
    const char* pb = (const char*)sB + cur * BBUFB;
    f16x8 af[2][2], bf[4][2];
    #pragma unroll
    for (int mi = 0; mi < 2; ++mi)
      #pragma unroll
      for (int kk = 0; kk < 2; ++kk)
        af[mi][kk] = *(const f16x8*)(pa + aoff[mi][kk]);
    #pragma unroll
    for (int ni = 0; ni < 4; ++ni)
      #pragma unroll
      for (int kk = 0; kk < 2; ++kk)
        bf[ni][kk] = *(const f16x8*)(pb + boff[ni][kk]);
    #pragma unroll
    for (int kk = 0; kk < 2; ++kk)
      #pragma unroll
      for (int mi = 0; mi < 2; ++mi)
        #pragma unroll
        for (int ni = 0; ni < 4; ++ni)
          acc[mi][ni] = __builtin_amdgcn_mfma_f32_16x16x32_f16(af[mi][kk], bf[ni][kk], acc[mi][ni], 0, 0, 0);
    __syncthreads();
    cur ^= 1;
  }

  // ---- epilogue ----
  struct alignas(4 * sizeof(OutT)) Pack4 { OutT v[4]; };
  const int rr = (lane >> 4) * 4;
  #pragma unroll
  for (int mi = 0; mi < 2; ++mi) {
    int m0 = bm + wr * 32 + mi * 16 + rr;
    #pragma unroll
    for (int ni = 0; ni < 4; ++ni) {
      int n0 = bn + wc * 64 + ni * 16 + lm;
      f32x4 v = acc[mi][ni];
      float vals[4];
      #pragma unroll
      for (int r = 0; r < 4; ++r) {
        vals[r] = v[r];
        if (bias)  vals[r] += bias[m0 + r];
        if (resid) vals[r] += resid[(long)(m0 + r) * ldres + n0];
      }
      if (transw) {
        Pack4 pk;
        #pragma unroll
        for (int r = 0; r < 4; ++r) pk.v[r] = (OutT)vals[r];
        *(Pack4*)&C[(long)n0 * ldc + m0] = pk;
      } else {
        #pragma unroll
        for (int r = 0; r < 4; ++r)
          C[(long)(m0 + r) * ldc + n0] = (OutT)vals[r];
      }
    }
  }
}

// ---- merged conv GEMMs: z = cid*4 + b ----
__global__ __launch_bounds__(512) void conv_kernel(
    const f16* __restrict__ xcT, const f16* __restrict__ xsT,
    const f16* __restrict__ WnE, const float* __restrict__ bnE,
    const f16* __restrict__ WmE, const float* __restrict__ bmE,
    const f16* __restrict__ WlB, const float* __restrict__ bl,
    f16* __restrict__ MnT, f16* __restrict__ MmT, f16* __restrict__ Ml) {
  int bx = blockIdx.x, by = blockIdx.y, bz = blockIdx.z;
  xcd_swizzle(bx, by, bz);
  const int cid = bz >> 2, b = bz & 3;
  const f16* A; const float* bias; const f16* B; f16* C; int ldc; bool transw;
  if (cid == 0)      { A = WnE + (long)b*CC*CC; bias = bnE + b*CC; B = xcT + (long)b*TT*CC; C = MnT + (long)b*TT*CC; ldc = CC; transw = true; }
  else if (cid == 1) { A = WmE + (long)b*CC*CC; bias = bmE + b*CC; B = xsT + (long)b*TT*CC; C = MmT + (long)b*TT*CC; ldc = CC; transw = true; }
  else               { A = WlB;                 bias = bl;         B = xsT + (long)b*TT*CC; C = Ml  + (long)b*CC*TT; ldc = TT; transw = false; }
  gemm_core<128, 512, f16>(A, CC, B, CC, C, ldc, bias, nullptr, 0,
                           by * 128, bx * 128, CC, transw);
}

__global__ __launch_bounds__(512) void sgemm_kernel(
    const f16* __restrict__ MnT, const f16* __restrict__ MmT, f16* __restrict__ S) {
  int bx = blockIdx.x, by = blockIdx.y, bz = blockIdx.z;
  xcd_swizzle(bx, by, bz);
  gemm_core<128, 512, f16>(MnT + (long)bz*TT*CC, CC, MmT + (long)bz*TT*CC, CC,
                           S + (long)bz*TT*TT, TT, nullptr, nullptr, 0,
                           by * 128, bx * 128, CC, false);
}

__global__ __launch_bounds__(256) void pv_kernel(
    const f16* __restrict__ P, const f16* __restrict__ Ml, f16* __restrict__ MoT) {
  int bx = blockIdx.x, by = blockIdx.y, bz = blockIdx.z;
  xcd_swizzle(bx, by, bz);
  gemm_core<64, 256, f16>(P + (long)bz*TT*TT, TT, Ml + (long)bz*CC*TT, TT,
                          MoT + (long)bz*TT*CC, CC, nullptr, nullptr, 0,
                          by * 64, bx * 128, TT, false);
}

__global__ __launch_bounds__(256) void out_kernel(
    const f16* __restrict__ WoB, const f16* __restrict__ MoT,
    const float* __restrict__ bo, const float* __restrict__ xc, float* __restrict__ out) {
  int bx = blockIdx.x, by = blockIdx.y, bz = blockIdx.z;
  xcd_swizzle(bx, by, bz);
  gemm_core<64, 256, float>(WoB, CC, MoT + (long)bz*TT*CC, CC,
                            out + (long)bz*CC*TT, TT, bo, xc + (long)bz*CC*TT, TT,
                            by * 64, bx * 128, CC, false);
}

extern "C" void kernel_launch(void* const* d_in, const int* in_sizes, int n_in,
                              void* d_out, int out_size, void* d_ws, size_t ws_size,
                              hipStream_t stream) {
  const float* x_c = (const float*)d_in[0];
  const float* x_s = (const float*)d_in[1];
  const float* Wn  = (const float*)d_in[2];
  const float* bn  = (const float*)d_in[3];
  const float* Wm  = (const float*)d_in[4];
  const float* bm  = (const float*)d_in[5];
  const float* Wl  = (const float*)d_in[6];
  const float* bl  = (const float*)d_in[7];
  const float* Wo  = (const float*)d_in[8];
  const float* bo  = (const float*)d_in[9];
  float* out = (float*)d_out;

  char* w = (char*)d_ws;
  auto alloc = [&](size_t bytes) { char* p = w; w += (bytes + 255) & ~(size_t)255; return p; };
  float* sumc = (float*)alloc(BB * CC * 4);
  float* sqc  = (float*)alloc(BB * CC * 4);
  float* sums_ = (float*)alloc(BB * CC * 4);
  float* sqs  = (float*)alloc(BB * CC * 4);
  float* bnE  = (float*)alloc(BB * CC * 4);
  float* bmE  = (float*)alloc(BB * CC * 4);
  f16* WnE = (f16*)alloc((size_t)BB * CC * CC * 2);
  f16* WmE = (f16*)alloc((size_t)BB * CC * CC * 2);
  f16* WlB = (f16*)alloc((size_t)CC * CC * 2);
  f16* WoB = (f16*)alloc((size_t)CC * CC * 2);
  f16* xcT = (f16*)alloc((size_t)BB * TT * CC * 2);
  f16* xsT = (f16*)alloc((size_t)BB * TT * CC * 2);
  f16* MnT = (f16*)alloc((size_t)BB * TT * CC * 2);
  f16* MmT = (f16*)alloc((size_t)BB * TT * CC * 2);
  f16* Ml  = (f16*)alloc((size_t)BB * CC * TT * 2);
  f16* S   = (f16*)alloc((size_t)BB * TT * TT * 2);
  f16* MoT = (f16*)alloc((size_t)BB * TT * CC * 2);

  // zero the 4 stat arrays (contiguous, 4*BB*CC floats)
  hipMemsetAsync(sumc, 0, (size_t)4 * BB * CC * 4, stream);

  transpose_kernel<<<dim3(TT / 64, CC / 64, BB * 2), dim3(256), 0, stream>>>(
      x_c, x_s, xcT, xsT, sumc, sqc, sums_, sqs);
  prepw_kernel<<<dim3(CC, BB), dim3(256), 0, stream>>>(Wn, bn, sumc, sqc, WnE, bnE);
  prepw_kernel<<<dim3(CC, BB), dim3(256), 0, stream>>>(Wm, bm, sums_, sqs, WmE, bmE);
  f2h_kernel<<<dim3(CC * CC / (256 * 8)), dim3(256), 0, stream>>>(Wl, WlB);
  f2h_kernel<<<dim3(CC * CC / (256 * 8)), dim3(256), 0, stream>>>(Wo, WoB);

  conv_kernel<<<dim3(16, 4, 12), dim3(512), 0, stream>>>(
      xcT, xsT, WnE, bnE, WmE, bmE, WlB, bl, MnT, MmT, Ml);
  sgemm_kernel<<<dim3(16, 16, BB), dim3(512), 0, stream>>>(MnT, MmT, S);
  softmax_kernel<<<dim3(TT, BB), dim3(256), 0, stream>>>(S);
  pv_kernel<<<dim3(4, 32, BB), dim3(256), 0, stream>>>(S, Ml, MoT);
  out_kernel<<<dim3(16, 8, BB), dim3(256), 0, stream>>>(WoB, MoT, bo, x_c, out);
}

// Round 6
// 227.014 us; speedup vs baseline: 1.1845x; 1.0343x over previous
//
#include <hip/hip_runtime.h>
#include <hip/hip_bf16.h>
#include <stdint.h>

typedef _Float16 f16;
typedef _Float16 f16x8 __attribute__((ext_vector_type(8)));
typedef _Float16 f16x4 __attribute__((ext_vector_type(4)));
typedef float    f32x4 __attribute__((ext_vector_type(4)));

#define BB 4
#define CC 512
#define TT 2048

__device__ __forceinline__ void gload16(const void* g, void* l) {
  __builtin_amdgcn_global_load_lds((const __attribute__((address_space(1))) void*)g,
                                   (__attribute__((address_space(3))) void*)l, 16, 0, 0);
}

template <int N>
__device__ __forceinline__ void s_wait_vmcnt() {
  if constexpr (N == 0)      asm volatile("s_waitcnt vmcnt(0)" ::: "memory");
  else if constexpr (N == 4) asm volatile("s_waitcnt vmcnt(4)" ::: "memory");
  else if constexpr (N == 6) asm volatile("s_waitcnt vmcnt(6)" ::: "memory");
}

// XCD-chunked bijective block swizzle (requires total % 8 == 0)
__device__ __forceinline__ void xcd_swizzle(int& bx, int& by, int& bz) {
  int gx = gridDim.x, gy = gridDim.y;
  int F = bx + gx * (by + gy * bz);
  int q = (gx * gy * gridDim.z) >> 3;
  int l = (F & 7) * q + (F >> 3);
  bx = l % gx; by = (l / gx) % gy; bz = l / (gx * gy);
}

// ---------------- f32 [C][T] -> f16 [T][C] transpose + fused instance-norm sums ----------------
__global__ __launch_bounds__(256) void transpose_kernel(
    const float* __restrict__ xc, const float* __restrict__ xs,
    f16* __restrict__ xcT, f16* __restrict__ xsT,
    float* __restrict__ sumc, float* __restrict__ sqc,
    float* __restrict__ sums_, float* __restrict__ sqs) {
  const int b = blockIdx.z & 3, which = blockIdx.z >> 2;
  const float* src = (which ? xs : xc) + (long)b * CC * TT;
  f16* dst = (which ? xsT : xcT) + (long)b * TT * CC;
  float* sumP = (which ? sums_ : sumc) + b * CC;
  float* sqP  = (which ? sqs   : sqc ) + b * CC;
  const int t0 = blockIdx.x * 64, c0 = blockIdx.y * 64;
  __shared__ float tile[64][65];
  const int tid = threadIdx.x;
  #pragma unroll
  for (int it = 0; it < 4; ++it) {
    int s = it * 256 + tid, r = s >> 4, q = s & 15;
    float4 v = *(const float4*)&src[(long)(c0 + r) * TT + t0 + q * 4];
    tile[r][q*4+0] = v.x; tile[r][q*4+1] = v.y; tile[r][q*4+2] = v.z; tile[r][q*4+3] = v.w;
    float ps = v.x + v.y + v.z + v.w;
    float pq = v.x*v.x + v.y*v.y + v.z*v.z + v.w*v.w;
    #pragma unroll
    for (int o = 8; o; o >>= 1) { ps += __shfl_xor(ps, o); pq += __shfl_xor(pq, o); }
    if ((tid & 15) == 0) {
      atomicAdd(&sumP[c0 + r], ps);
      atomicAdd(&sqP [c0 + r], pq);
    }
  }
  __syncthreads();
  #pragma unroll
  for (int it = 0; it < 4; ++it) {
    int s = it * 256 + tid, r = s >> 4, q = s & 15;
    f16x4 o;
    o[0] = (f16)tile[q*4+0][r]; o[1] = (f16)tile[q*4+1][r];
    o[2] = (f16)tile[q*4+2][r]; o[3] = (f16)tile[q*4+3][r];
    *(f16x4*)&dst[(long)(t0 + r) * CC + c0 + q * 4] = o;
  }
}

// ---------------- fold instance-norm into conv weights (from raw sums) ----------------
__global__ __launch_bounds__(256) void prepw_kernel(
    const float* __restrict__ W, const float* __restrict__ bias,
    const float* __restrict__ sum, const float* __restrict__ sq,
    f16* __restrict__ Weff, float* __restrict__ beff) {
  const int o = blockIdx.x, b = blockIdx.y, tid = threadIdx.x;
  float acc = 0.f;
  #pragma unroll
  for (int j = 0; j < 2; ++j) {
    int c = tid + j * 256;
    float mean = sum[b * CC + c] * (1.f / TT);
    float var  = sq [b * CC + c] * (1.f / TT) - mean * mean;
    float iv = 1.0f / sqrtf(var + 1e-5f);
    float wv = W[(long)o * CC + c] * iv;
    Weff[((long)b * CC + o) * CC + c] = (f16)wv;
    acc += wv * mean;
  }
  #pragma unroll
  for (int off = 32; off; off >>= 1) acc += __shfl_xor(acc, off);
  __shared__ float red[4];
  if ((tid & 63) == 0) red[tid >> 6] = acc;
  __syncthreads();
  if (tid == 0) beff[b * CC + o] = bias[o] - (red[0] + red[1] + red[2] + red[3]);
}

// ---------------- f32 -> f16 convert ----------------
__global__ __launch_bounds__(256) void f2h_kernel(const float* __restrict__ src,
                                                  f16* __restrict__ dst) {
  long i = ((long)blockIdx.x * 256 + threadIdx.x) * 8;
  float4 a = *(const float4*)&src[i], d = *(const float4*)&src[i + 4];
  f16x8 o;
  o[0]=(f16)a.x; o[1]=(f16)a.y; o[2]=(f16)a.z; o[3]=(f16)a.w;
  o[4]=(f16)d.x; o[5]=(f16)d.y; o[6]=(f16)d.z; o[7]=(f16)d.w;
  *(f16x8*)&dst[i] = o;
}

// ---------------- row softmax over f16 S, in place ----------------
__global__ __launch_bounds__(256) void softmax_kernel(f16* __restrict__ S) {
  f16* p = S + ((long)blockIdx.y * TT + blockIdx.x) * TT;
  const int tid = threadIdx.x;
  f16x8 v8 = ((const f16x8*)p)[tid];
  float v[8];
  #pragma unroll
  for (int j = 0; j < 8; ++j) v[j] = (float)v8[j];
  float m = v[0];
  #pragma unroll
  for (int j = 1; j < 8; ++j) m = fmaxf(m, v[j]);
  #pragma unroll
  for (int o = 32; o; o >>= 1) m = fmaxf(m, __shfl_xor(m, o));
  __shared__ float red[4], red2[4];
  if (!(tid & 63)) red[tid >> 6] = m;
  __syncthreads();
  m = fmaxf(fmaxf(red[0], red[1]), fmaxf(red[2], red[3]));
  float e[8], sum = 0.f;
  #pragma unroll
  for (int j = 0; j < 8; ++j) { e[j] = __expf(v[j] - m); sum += e[j]; }
  #pragma unroll
  for (int o = 32; o; o >>= 1) sum += __shfl_xor(sum, o);
  if (!(tid & 63)) red2[tid >> 6] = sum;
  __syncthreads();
  sum = red2[0] + red2[1] + red2[2] + red2[3];
  float is = 1.f / sum;
  f16x8 o8;
  #pragma unroll
  for (int j = 0; j < 8; ++j) o8[j] = (f16)(e[j] * is);
  ((f16x8*)p)[tid] = o8;
}

// ============== triple-buffer depth-2 prefetch GEMM core (counted vmcnt) ==============
// C[M,N] = A[M,K] * BT[N,K]^T. Tile BM x 128, BK=64, NT threads.
// Wave grid: wr = wv>>1 (M), wc = wv&1 (N); wave tile 32x64, acc[2][4].
// LDS XOR-swizzle (row&7)<<4 on staging SOURCE + ds_read (dest linear).
// Pipeline: stage(kt+2) issued at iter kt; leading s_waitcnt vmcnt(LOADS)+s_barrier
// publishes tile kt while tile kt+1 stays in flight (never drain to 0 mid-loop).
template <int BM, int NT, typename OutT>
__device__ __forceinline__ void gemm_core(
    const f16* __restrict__ A, int lda,
    const f16* __restrict__ BT, int ldb,
    OutT* __restrict__ C, int ldc,
    const float* __restrict__ bias,
    const float* __restrict__ resid, int ldres,
    int bm, int bn, int K, bool transw) {

  constexpr int CA = BM * 8 / NT;          // A chunks per thread
  constexpr int CB = 128 * 8 / NT;         // B chunks per thread
  constexpr int LOADS = CA + CB;           // gload16 per stage per thread
  constexpr int ABUFB = BM * 128;          // bytes per A buffer
  constexpr int BBUFB = 128 * 128;         // bytes per B buffer

  __shared__ f16 sA[3 * BM * 64];
  __shared__ f16 sB[3 * 128 * 64];

  const int tid = threadIdx.x, lane = tid & 63, wv = tid >> 6;
  const int wr = wv >> 1, wc = wv & 1;

  // ---- staging addresses ----
  const char* gAp[CA]; int lAo[CA];
  #pragma unroll
  for (int i = 0; i < CA; ++i) {
    int cid = tid + i * NT, row = cid >> 3;
    int colb = ((cid & 7) * 16) ^ ((row & 7) << 4);
    gAp[i] = (const char*)A + (long)(bm + row) * lda * 2 + colb;
    lAo[i] = cid * 16;
  }
  const char* gBp[CB]; int lBo[CB];
  #pragma unroll
  for (int i = 0; i < CB; ++i) {
    int cid = tid + i * NT, row = cid >> 3;
    int colb = ((cid & 7) * 16) ^ ((row & 7) << 4);
    gBp[i] = (const char*)BT + (long)(bn + row) * ldb * 2 + colb;
    lBo[i] = cid * 16;
  }

  // ---- fragment ds_read byte offsets ----
  const int lm = lane & 15, lkb = (lane >> 4) * 16, sw = (lane & 7) << 4;
  int aoff[2][2], boff[4][2];
  #pragma unroll
  for (int mi = 0; mi < 2; ++mi) {
    int r = wr * 32 + mi * 16 + lm;
    #pragma unroll
    for (int kk = 0; kk < 2; ++kk)
      aoff[mi][kk] = r * 128 + ((kk * 64 + lkb) ^ sw);
  }
  #pragma unroll
  for (int ni = 0; ni < 4; ++ni) {
    int r = wc * 64 + ni * 16 + lm;
    #pragma unroll
    for (int kk = 0; kk < 2; ++kk)
      boff[ni][kk] = r * 128 + ((kk * 64 + lkb) ^ sw);
  }

  f32x4 acc[2][4] = {};
  const int nk = K >> 6;

  // prologue: stage tiles 0 and 1 into slots 0,1
  #pragma unroll
  for (int i = 0; i < CA; ++i) gload16(gAp[i], (char*)sA + lAo[i]);
  #pragma unroll
  for (int i = 0; i < CB; ++i) gload16(gBp[i], (char*)sB + lBo[i]);
  #pragma unroll
  for (int i = 0; i < CA; ++i) gload16(gAp[i] + 128, (char*)sA + ABUFB + lAo[i]);
  #pragma unroll
  for (int i = 0; i < CB; ++i) gload16(gBp[i] + 128, (char*)sB + BBUFB + lBo[i]);

  int s0 = 0;  // slot holding tile kt
  for (int kt = 0; kt < nk; ++kt) {
    // publish tile kt (tile kt+1 stays in flight)
    if (kt + 1 < nk) s_wait_vmcnt<LOADS>(); else s_wait_vmcnt<0>();
    __builtin_amdgcn_s_barrier();

    // issue tile kt+2 into slot (s0+2)%3
    if (kt + 2 < nk) {
      int s2 = s0 + 2; if (s2 >= 3) s2 -= 3;
      long kb = (long)(kt + 2) * 128;
      int na = s2 * ABUFB, nb = s2 * BBUFB;
      #pragma unroll
      for (int i = 0; i < CA; ++i) gload16(gAp[i] + kb, (char*)sA + na + lAo[i]);
      #pragma unroll
      for (int i = 0; i < CB; ++i) gload16(gBp[i] + kb, (char*)sB + nb + lBo[i]);
    }

    const char* pa = (const char*)sA + s0 * ABUFB;
    const char* pb = (const char*)sB + s0 * BBUFB;
    f16x8 af[2][2], bf[4][2];
    #pragma unroll
    for (int mi = 0; mi < 2; ++mi)
      #pragma unroll
      for (int kk = 0; kk < 2; ++kk)
        af[mi][kk] = *(const f16x8*)(pa + aoff[mi][kk]);
    #pragma unroll
    for (int ni = 0; ni < 4; ++ni)
      #pragma unroll
      for (int kk = 0; kk < 2; ++kk)
        bf[ni][kk] = *(const f16x8*)(pb + boff[ni][kk]);
    #pragma unroll
    for (int kk = 0; kk < 2; ++kk)
      #pragma unroll
      for (int mi = 0; mi < 2; ++mi)
        #pragma unroll
        for (int ni = 0; ni < 4; ++ni)
          acc[mi][ni] = __builtin_amdgcn_mfma_f32_16x16x32_f16(af[mi][kk], bf[ni][kk], acc[mi][ni], 0, 0, 0);

    // rendezvous: all waves done reading slot s0 before it is restaged (at kt+3)
    __builtin_amdgcn_s_barrier();
    s0 = (s0 == 2) ? 0 : s0 + 1;
  }

  // ---- epilogue ----
  struct alignas(4 * sizeof(OutT)) Pack4 { OutT v[4]; };
  const int rr = (lane >> 4) * 4;
  #pragma unroll
  for (int mi = 0; mi < 2; ++mi) {
    int m0 = bm + wr * 32 + mi * 16 + rr;
    #pragma unroll
    for (int ni = 0; ni < 4; ++ni) {
      int n0 = bn + wc * 64 + ni * 16 + lm;
      f32x4 v = acc[mi][ni];
      float vals[4];
      #pragma unroll
      for (int r = 0; r < 4; ++r) {
        vals[r] = v[r];
        if (bias)  vals[r] += bias[m0 + r];
        if (resid) vals[r] += resid[(long)(m0 + r) * ldres + n0];
      }
      if (transw) {
        Pack4 pk;
        #pragma unroll
        for (int r = 0; r < 4; ++r) pk.v[r] = (OutT)vals[r];
        *(Pack4*)&C[(long)n0 * ldc + m0] = pk;
      } else {
        #pragma unroll
        for (int r = 0; r < 4; ++r)
          C[(long)(m0 + r) * ldc + n0] = (OutT)vals[r];
      }
    }
  }
}

// ---- merged conv GEMMs: z = cid*4 + b ----
__global__ __launch_bounds__(512) void conv_kernel(
    const f16* __restrict__ xcT, const f16* __restrict__ xsT,
    const f16* __restrict__ WnE, const float* __restrict__ bnE,
    const f16* __restrict__ WmE, const float* __restrict__ bmE,
    const f16* __restrict__ WlB, const float* __restrict__ bl,
    f16* __restrict__ MnT, f16* __restrict__ MmT, f16* __restrict__ Ml) {
  int bx = blockIdx.x, by = blockIdx.y, bz = blockIdx.z;
  xcd_swizzle(bx, by, bz);
  const int cid = bz >> 2, b = bz & 3;
  const f16* A; const float* bias; const f16* B; f16* C; int ldc; bool transw;
  if (cid == 0)      { A = WnE + (long)b*CC*CC; bias = bnE + b*CC; B = xcT + (long)b*TT*CC; C = MnT + (long)b*TT*CC; ldc = CC; transw = true; }
  else if (cid == 1) { A = WmE + (long)b*CC*CC; bias = bmE + b*CC; B = xsT + (long)b*TT*CC; C = MmT + (long)b*TT*CC; ldc = CC; transw = true; }
  else               { A = WlB;                 bias = bl;         B = xsT + (long)b*TT*CC; C = Ml  + (long)b*CC*TT; ldc = TT; transw = false; }
  gemm_core<128, 512, f16>(A, CC, B, CC, C, ldc, bias, nullptr, 0,
                           by * 128, bx * 128, CC, transw);
}

__global__ __launch_bounds__(512) void sgemm_kernel(
    const f16* __restrict__ MnT, const f16* __restrict__ MmT, f16* __restrict__ S) {
  int bx = blockIdx.x, by = blockIdx.y, bz = blockIdx.z;
  xcd_swizzle(bx, by, bz);
  gemm_core<128, 512, f16>(MnT + (long)bz*TT*CC, CC, MmT + (long)bz*TT*CC, CC,
                           S + (long)bz*TT*TT, TT, nullptr, nullptr, 0,
                           by * 128, bx * 128, CC, false);
}

__global__ __launch_bounds__(256) void pv_kernel(
    const f16* __restrict__ P, const f16* __restrict__ Ml, f16* __restrict__ MoT) {
  int bx = blockIdx.x, by = blockIdx.y, bz = blockIdx.z;
  xcd_swizzle(bx, by, bz);
  gemm_core<64, 256, f16>(P + (long)bz*TT*TT, TT, Ml + (long)bz*CC*TT, TT,
                          MoT + (long)bz*TT*CC, CC, nullptr, nullptr, 0,
                          by * 64, bx * 128, TT, false);
}

__global__ __launch_bounds__(256) void out_kernel(
    const f16* __restrict__ WoB, const f16* __restrict__ MoT,
    const float* __restrict__ bo, const float* __restrict__ xc, float* __restrict__ out) {
  int bx = blockIdx.x, by = blockIdx.y, bz = blockIdx.z;
  xcd_swizzle(bx, by, bz);
  gemm_core<64, 256, float>(WoB, CC, MoT + (long)bz*TT*CC, CC,
                            out + (long)bz*CC*TT, TT, bo, xc + (long)bz*CC*TT, TT,
                            by * 64, bx * 128, CC, false);
}

extern "C" void kernel_launch(void* const* d_in, const int* in_sizes, int n_in,
                              void* d_out, int out_size, void* d_ws, size_t ws_size,
                              hipStream_t stream) {
  const float* x_c = (const float*)d_in[0];
  const float* x_s = (const float*)d_in[1];
  const float* Wn  = (const float*)d_in[2];
  const float* bn  = (const float*)d_in[3];
  const float* Wm  = (const float*)d_in[4];
  const float* bm  = (const float*)d_in[5];
  const float* Wl  = (const float*)d_in[6];
  const float* bl  = (const float*)d_in[7];
  const float* Wo  = (const float*)d_in[8];
  const float* bo  = (const float*)d_in[9];
  float* out = (float*)d_out;

  char* w = (char*)d_ws;
  auto alloc = [&](size_t bytes) { char* p = w; w += (bytes + 255) & ~(size_t)255; return p; };
  float* sumc = (float*)alloc(BB * CC * 4);
  float* sqc  = (float*)alloc(BB * CC * 4);
  float* sums_ = (float*)alloc(BB * CC * 4);
  float* sqs  = (float*)alloc(BB * CC * 4);
  float* bnE  = (float*)alloc(BB * CC * 4);
  float* bmE  = (float*)alloc(BB * CC * 4);
  f16* WnE = (f16*)alloc((size_t)BB * CC * CC * 2);
  f16* WmE = (f16*)alloc((size_t)BB * CC * CC * 2);
  f16* WlB = (f16*)alloc((size_t)CC * CC * 2);
  f16* WoB = (f16*)alloc((size_t)CC * CC * 2);
  f16* xcT = (f16*)alloc((size_t)BB * TT * CC * 2);
  f16* xsT = (f16*)alloc((size_t)BB * TT * CC * 2);
  f16* MnT = (f16*)alloc((size_t)BB * TT * CC * 2);
  f16* MmT = (f16*)alloc((size_t)BB * TT * CC * 2);
  f16* Ml  = (f16*)alloc((size_t)BB * CC * TT * 2);
  f16* S   = (f16*)alloc((size_t)BB * TT * TT * 2);
  f16* MoT = (f16*)alloc((size_t)BB * TT * CC * 2);

  // zero the 4 stat arrays (contiguous, 4*BB*CC floats)
  hipMemsetAsync(sumc, 0, (size_t)4 * BB * CC * 4, stream);

  transpose_kernel<<<dim3(TT / 64, CC / 64, BB * 2), dim3(256), 0, stream>>>(
      x_c, x_s, xcT, xsT, sumc, sqc, sums_, sqs);
  prepw_kernel<<<dim3(CC, BB), dim3(256), 0, stream>>>(Wn, bn, sumc, sqc, WnE, bnE);
  prepw_kernel<<<dim3(CC, BB), dim3(256), 0, stream>>>(Wm, bm, sums_, sqs, WmE, bmE);
  f2h_kernel<<<dim3(CC * CC / (256 * 8)), dim3(256), 0, stream>>>(Wl, WlB);
  f2h_kernel<<<dim3(CC * CC / (256 * 8)), dim3(256), 0, stream>>>(Wo, WoB);

  conv_kernel<<<dim3(16, 4, 12), dim3(512), 0, stream>>>(
      xcT, xsT, WnE, bnE, WmE, bmE, WlB, bl, MnT, MmT, Ml);
  sgemm_kernel<<<dim3(16, 16, BB), dim3(512), 0, stream>>>(MnT, MmT, S);
  softmax_kernel<<<dim3(TT, BB), dim3(256), 0, stream>>>(S);
  pv_kernel<<<dim3(4, 32, BB), dim3(256), 0, stream>>>(S, Ml, MoT);
  out_kernel<<<dim3(16, 8, BB), dim3(256), 0, stream>>>(WoB, MoT, bo, x_c, out);
}